// Round 1
// baseline (982.965 us; speedup 1.0000x reference)
//
#include <hip/hip_runtime.h>
#include <math.h>

#define HW 128
#define HW2 (HW * HW)
#define HH 64
#define CC 64
#define BB 2
#define NDG 8
#define CPG 8
#define KK2 9

// ---------------------------------------------------------------------------
// bilinear upsample x2, align_corners=True, with output scale multiplier
// in: [B*CC, 64, 64]  out: [B*CC, 128, 128]
// ---------------------------------------------------------------------------
__global__ __launch_bounds__(256) void up2_kernel(const float* __restrict__ in,
                                                  float* __restrict__ out,
                                                  float scale) {
    int idx = blockIdx.x * 256 + threadIdx.x;           // over B*CC*128*128
    int x = idx & 127;
    int y = (idx >> 7) & 127;
    int c = idx >> 14;                                   // [0, B*CC)
    const float f = 63.0f / 127.0f;
    float cy = y * f, cx = x * f;
    float y0f = floorf(cy), x0f = floorf(cx);
    int y0 = (int)y0f, x0 = (int)x0f;
    int y1 = min(y0 + 1, HH - 1), x1 = min(x0 + 1, HH - 1);
    float fy = cy - y0f, fx = cx - x0f;
    const float* p = in + (size_t)c * (HH * HH);
    float v00 = p[y0 * HH + x0], v01 = p[y0 * HH + x1];
    float v10 = p[y1 * HH + x0], v11 = p[y1 * HH + x1];
    float t0 = v00 * (1.0f - fy) + v10 * fy;
    float t1 = v01 * (1.0f - fy) + v11 * fy;
    out[idx] = (t0 * (1.0f - fx) + t1 * fx) * scale;
}

// ---------------------------------------------------------------------------
// generic 3x3 conv, pad=1, dual input (implicit concat), 4 out-ch per thread
// w layout: [Cout][Ca+Cb][3][3]
// ---------------------------------------------------------------------------
__device__ __forceinline__ void conv_in(const float* __restrict__ in, int Cthis,
                                        const float* __restrict__ wp, int wstride,
                                        int x, int y,
                                        float& a0, float& a1, float& a2, float& a3) {
    for (int ci = 0; ci < Cthis; ++ci) {
        const float* src = in + (size_t)ci * HW2;
        const float* wr = wp + ci * 9;
#pragma unroll
        for (int ky = 0; ky < 3; ++ky) {
            int yy = y + ky - 1;
            float i0 = 0.f, i1 = 0.f, i2 = 0.f;
            if ((unsigned)yy < (unsigned)HW) {
                const float* row = src + yy * HW;
                i1 = row[x];
                i0 = (x > 0) ? row[x - 1] : 0.f;
                i2 = (x < HW - 1) ? row[x + 1] : 0.f;
            }
            const float* wk = wr + ky * 3;
            a0 += i0 * wk[0]             + i1 * wk[1]             + i2 * wk[2];
            a1 += i0 * wk[wstride]       + i1 * wk[wstride + 1]   + i2 * wk[wstride + 2];
            a2 += i0 * wk[2 * wstride]   + i1 * wk[2 * wstride + 1] + i2 * wk[2 * wstride + 2];
            a3 += i0 * wk[3 * wstride]   + i1 * wk[3 * wstride + 1] + i2 * wk[3 * wstride + 2];
        }
    }
}

__global__ __launch_bounds__(256) void conv3x3_kernel(
    const float* __restrict__ inA, int Ca,
    const float* __restrict__ inB, int Cb,
    const float* __restrict__ w, const float* __restrict__ bias,
    float* __restrict__ out, int Cout, int act) {
    int tid = threadIdx.x;
    int x = tid & 127;
    int y = (blockIdx.x << 1) | (tid >> 7);
    int cob = blockIdx.y << 2;
    int b = blockIdx.z;
    int Cin = Ca + Cb;
    int wstride = Cin * 9;
    float a0 = bias[cob + 0], a1 = bias[cob + 1], a2 = bias[cob + 2], a3 = bias[cob + 3];
    const float* wp = w + (size_t)cob * wstride;
    conv_in(inA + (size_t)b * Ca * HW2, Ca, wp, wstride, x, y, a0, a1, a2, a3);
    if (Cb > 0)
        conv_in(inB + (size_t)b * Cb * HW2, Cb, wp + Ca * 9, wstride, x, y, a0, a1, a2, a3);
    if (act == 1) {
        a0 = (a0 >= 0.f) ? a0 : 0.1f * a0;
        a1 = (a1 >= 0.f) ? a1 : 0.1f * a1;
        a2 = (a2 >= 0.f) ? a2 : 0.1f * a2;
        a3 = (a3 >= 0.f) ? a3 : 0.1f * a3;
    }
    size_t base = ((size_t)(b * Cout + cob)) * HW2 + y * HW + x;
    out[base] = a0;
    out[base + HW2] = a1;
    out[base + 2 * HW2] = a2;
    out[base + 3 * HW2] = a3;
}

// ---------------------------------------------------------------------------
// DCNv2 sampling: build val[B][576][H][W], channel c' = g*72 + c*9 + k
// co: [B][216][H][W]  (72 off_y | 72 off_x | 72 mask-logit)
// ---------------------------------------------------------------------------
__global__ __launch_bounds__(256) void dcn_sample_kernel(
    const float* __restrict__ xin, const float* __restrict__ co,
    float* __restrict__ val) {
    int p = blockIdx.x * 256 + threadIdx.x;   // pixel
    int xpix = p & 127, ypix = p >> 7;
    int gk = blockIdx.y;                      // g*9 + k, 72 values
    int g = gk / 9, k = gk - g * 9;
    int b = blockIdx.z;

    float offy = co[((size_t)(b * 216 + gk)) * HW2 + p];
    float offx = co[((size_t)(b * 216 + 72 + gk)) * HW2 + p];
    float mv = co[((size_t)(b * 216 + 144 + gk)) * HW2 + p];
    mv = 1.0f / (1.0f + expf(-mv));

    int ky = k / 3 - 1, kx = k - (k / 3) * 3 - 1;
    float py = offy + (float)ky + (float)ypix;
    float px = offx + (float)kx + (float)xpix;
    float y0f = floorf(py), x0f = floorf(px);
    float wy = py - y0f, wx = px - x0f;
    int y0 = (int)y0f, x0 = (int)x0f;
    int y1 = y0 + 1, x1 = x0 + 1;

    bool vy0 = (y0 >= 0) && (y0 < HW), vy1 = (y1 >= 0) && (y1 < HW);
    bool vx0 = (x0 >= 0) && (x0 < HW), vx1 = (x1 >= 0) && (x1 < HW);
    float w00 = (1.f - wy) * (1.f - wx) * ((vy0 && vx0) ? 1.f : 0.f);
    float w01 = (1.f - wy) * wx         * ((vy0 && vx1) ? 1.f : 0.f);
    float w10 = wy * (1.f - wx)         * ((vy1 && vx0) ? 1.f : 0.f);
    float w11 = wy * wx                 * ((vy1 && vx1) ? 1.f : 0.f);

    int y0c = min(max(y0, 0), HW - 1), y1c = min(max(y1, 0), HW - 1);
    int x0c = min(max(x0, 0), HW - 1), x1c = min(max(x1, 0), HW - 1);
    int i00 = y0c * HW + x0c, i01 = y0c * HW + x1c;
    int i10 = y1c * HW + x0c, i11 = y1c * HW + x1c;

    const float* xp = xin + ((size_t)b * CC + g * CPG) * HW2;
    float* vp = val + ((size_t)b * 576 + (size_t)(g * 72 + k)) * HW2 + p;
#pragma unroll
    for (int c = 0; c < CPG; ++c) {
        const float* ch = xp + (size_t)c * HW2;
        float v = w00 * ch[i00] + w01 * ch[i01] + w10 * ch[i10] + w11 * ch[i11];
        vp[(size_t)c * 9 * HW2] = v * mv;
    }
}

// ---------------------------------------------------------------------------
// 1x1 GEMM: out[b,o,p] = bias[o] + sum_{c'=0..575} w[o*576+c'] * val[b,c',p]
// (w_dcn flat layout [o][ci][3][3] == [o][g*72+c*9+k] matches val channels)
// ---------------------------------------------------------------------------
__global__ __launch_bounds__(256) void dcn_gemm_kernel(
    const float* __restrict__ val, const float* __restrict__ w,
    const float* __restrict__ bias, float* __restrict__ out) {
    int p = blockIdx.x * 256 + threadIdx.x;
    int ob = blockIdx.y << 2;
    int b = blockIdx.z;
    const float* vp = val + (size_t)b * 576 * HW2 + p;
    const float* w0 = w + (size_t)ob * 576;
    float a0 = bias[ob], a1 = bias[ob + 1], a2 = bias[ob + 2], a3 = bias[ob + 3];
    for (int c = 0; c < 576; ++c) {
        float v = vp[(size_t)c * HW2];
        a0 += v * w0[c];
        a1 += v * w0[576 + c];
        a2 += v * w0[1152 + c];
        a3 += v * w0[1728 + c];
    }
    size_t base = ((size_t)(b * CC + ob)) * HW2 + p;
    out[base] = a0;
    out[base + HW2] = a1;
    out[base + 2 * HW2] = a2;
    out[base + 3 * HW2] = a3;
}

// ---------------------------------------------------------------------------
extern "C" void kernel_launch(void* const* d_in, const int* in_sizes, int n_in,
                              void* d_out, int out_size, void* d_ws, size_t ws_size,
                              hipStream_t stream) {
    const float* x        = (const float*)d_in[0];
    const float* y        = (const float*)d_in[1];
    const float* prev_off = (const float*)d_in[2];
    const float* prev_fea = (const float*)d_in[3];
    const float* w1 = (const float*)d_in[4];  const float* b1 = (const float*)d_in[5];
    const float* w2 = (const float*)d_in[6];  const float* b2 = (const float*)d_in[7];
    const float* w3 = (const float*)d_in[8];  const float* b3 = (const float*)d_in[9];
    const float* w_off = (const float*)d_in[10]; const float* b_off = (const float*)d_in[11];
    const float* w_dcn = (const float*)d_in[12]; const float* b_dcn = (const float*)d_in[13];
    const float* w_fea = (const float*)d_in[14]; const float* b_fea = (const float*)d_in[15];

    float* out_off = (float*)d_out;                         // [2,64,128,128]
    float* out_out = (float*)d_out + (size_t)BB * CC * HW2; // [2,64,128,128]

    char* ws = (char*)d_ws;
    // lifetime-overlapped workspace plan (peak 66,060,288 B):
    float* bufU = (float*)(ws + 0);          // up(prev_offset)*2   8 MB  [steps 1-3]
    float* bufA = (float*)(ws + 8388608);    // off1                8 MB  [steps 2-3]
    float* bufB = (float*)(ws + 16777216);   // off2                8 MB  [steps 3-4]
    float* bufC = (float*)(ws + 0);          // co (216ch)       28.3 MB  [steps 5-6], reuses U/A/B
    float* bufV = (float*)(ws + 28311552);   // val (576ch)      37.7 MB  [steps 6-7]
    float* bufF = (float*)(ws + 0);          // fea                 8 MB  [steps 7-9], reuses C
    float* bufU2 = (float*)(ws + 8388608);   // up(prev_stage_fea)  8 MB  [steps 8-9]

    dim3 blk(256);
    dim3 gUp((BB * CC * HW2) / 256);
    dim3 gConv64(HW / 2, CC / 4, BB);
    dim3 gConv216(HW / 2, 216 / 4, BB);
    dim3 gSamp(HW2 / 256, NDG * KK2, BB);
    dim3 gGemm(HW2 / 256, CC / 4, BB);

    // 1. prev_offset -> up2 (*2 folded in)
    up2_kernel<<<gUp, blk, 0, stream>>>(prev_off, bufU, 2.0f);
    // 2. off1 = lrelu(conv(x || y, w1))
    conv3x3_kernel<<<gConv64, blk, 0, stream>>>(x, CC, y, CC, w1, b1, bufA, CC, 1);
    // 3. off2 = lrelu(conv(off1 || up_prev_off, w2))
    conv3x3_kernel<<<gConv64, blk, 0, stream>>>(bufA, CC, bufU, CC, w2, b2, bufB, CC, 1);
    // 4. off = lrelu(conv(off2, w3))  -> first output
    conv3x3_kernel<<<gConv64, blk, 0, stream>>>(bufB, CC, nullptr, 0, w3, b3, out_off, CC, 1);
    // 5. co = conv(off, w_off)  (216 ch, no act)
    conv3x3_kernel<<<gConv216, blk, 0, stream>>>(out_off, CC, nullptr, 0, w_off, b_off, bufC, 216, 0);
    // 6. val = dcn bilinear sampling + mask
    dcn_sample_kernel<<<gSamp, blk, 0, stream>>>(x, bufC, bufV);
    // 7. fea = w_dcn * val + b_dcn   (1x1 gemm over 576 ch)
    dcn_gemm_kernel<<<gGemm, blk, 0, stream>>>(bufV, w_dcn, b_dcn, bufF);
    // 8. up(prev_stage_fea)
    up2_kernel<<<gUp, blk, 0, stream>>>(prev_fea, bufU2, 1.0f);
    // 9. out = lrelu(conv(fea || up_fea, w_fea)) -> second output
    conv3x3_kernel<<<gConv64, blk, 0, stream>>>(bufF, CC, bufU2, CC, w_fea, b_fea, out_out, CC, 1);
}

// Round 2
// 300.466 us; speedup vs baseline: 3.2715x; 3.2715x over previous
//
#include <hip/hip_runtime.h>
#include <math.h>

typedef __bf16 bf16x8 __attribute__((ext_vector_type(8)));
typedef float f32x4 __attribute__((ext_vector_type(4)));
typedef unsigned short u16;

// ---------------- helpers ----------------
__device__ __forceinline__ u16 f2bf(float f) {
    unsigned int u = __builtin_bit_cast(unsigned int, f);
    unsigned int r = (u + 0x7FFFu + ((u >> 16) & 1u)) >> 16;   // RNE
    return (u16)r;
}
__device__ __forceinline__ float bf2f(u16 u) {
    unsigned int v = ((unsigned int)u) << 16;
    return __builtin_bit_cast(float, v);
}
__device__ __forceinline__ unsigned int pack2(float a, float b) {
    return (unsigned int)f2bf(a) | ((unsigned int)f2bf(b) << 16);
}
__device__ __forceinline__ bf16x8 ld8(const u16* p) {
    uint4 u = *reinterpret_cast<const uint4*>(p);
    return __builtin_bit_cast(bf16x8, u);
}

// ---------------- weight repack: [Co][Ci][3][3] f32 -> bf16 GEMM-A layout ----
// mode 0: dst[o*K + kk*Cin + ci]          (K = 9*Cin, shift-major)
// mode 1: dst[o*576 + (ci>>3)*72 + kk*8 + (ci&7)]   (dcn val order)
__global__ __launch_bounds__(256) void repack_w(const float* __restrict__ w,
                                                u16* __restrict__ dst,
                                                int Cout, int Cin, int K, int mode) {
    int idx = blockIdx.x * 256 + threadIdx.x;
    int total = Cout * Cin * 9;
    if (idx >= total) return;
    int kk = idx % 9;
    int t = idx / 9;
    int ci = t % Cin;
    int o = t / Cin;
    u16 v = f2bf(w[idx]);
    size_t d;
    if (mode == 0) d = (size_t)o * K + kk * Cin + ci;
    else           d = (size_t)o * 576 + (ci >> 3) * 72 + kk * 8 + (ci & 7);
    dst[d] = v;
}

// ---------------- NCHW f32 [B][64][128][128] -> NHWC-pad bf16 at channel c0 --
__global__ __launch_bounds__(256) void to_nhwc(const float* __restrict__ src,
                                               u16* __restrict__ dst,
                                               int c0, int Ctot) {
    int idx = blockIdx.x * 256 + threadIdx.x;   // b*16384 + pix
    int pix = idx & 16383, b = idx >> 14;
    int y = pix >> 7, x = pix & 127;
    const float* s = src + (size_t)b * 64 * 16384 + pix;
    u16* d = dst + (((size_t)b * 16900) + (size_t)(y + 1) * 130 + (x + 1)) * Ctot + c0;
#pragma unroll
    for (int q = 0; q < 8; ++q) {
        float v0 = s[(size_t)(q * 8 + 0) * 16384], v1 = s[(size_t)(q * 8 + 1) * 16384];
        float v2 = s[(size_t)(q * 8 + 2) * 16384], v3 = s[(size_t)(q * 8 + 3) * 16384];
        float v4 = s[(size_t)(q * 8 + 4) * 16384], v5 = s[(size_t)(q * 8 + 5) * 16384];
        float v6 = s[(size_t)(q * 8 + 6) * 16384], v7 = s[(size_t)(q * 8 + 7) * 16384];
        uint4 u;
        u.x = pack2(v0, v1); u.y = pack2(v2, v3); u.z = pack2(v4, v5); u.w = pack2(v6, v7);
        *reinterpret_cast<uint4*>(d + q * 8) = u;
    }
}

// ---------------- bilinear up2 (align_corners) + scale -> NHWC-pad bf16 ------
__global__ __launch_bounds__(256) void up2_nhwc(const float* __restrict__ src, // [B][64][64][64]
                                                u16* __restrict__ dst,
                                                int c0, int Ctot, float scale) {
    int idx = blockIdx.x * 256 + threadIdx.x;
    int pix = idx & 16383, b = idx >> 14;
    int y = pix >> 7, x = pix & 127;
    const float f = 63.0f / 127.0f;
    float cy = y * f, cx = x * f;
    float y0f = floorf(cy), x0f = floorf(cx);
    int y0 = (int)y0f, x0 = (int)x0f;
    int y1 = min(y0 + 1, 63), x1 = min(x0 + 1, 63);
    float fy = cy - y0f, fx = cx - x0f;
    float w00 = (1.f - fy) * (1.f - fx) * scale, w01 = (1.f - fy) * fx * scale;
    float w10 = fy * (1.f - fx) * scale, w11 = fy * fx * scale;
    int i00 = y0 * 64 + x0, i01 = y0 * 64 + x1, i10 = y1 * 64 + x0, i11 = y1 * 64 + x1;
    const float* s = src + (size_t)b * 64 * 4096;
    u16* d = dst + (((size_t)b * 16900) + (size_t)(y + 1) * 130 + (x + 1)) * Ctot + c0;
#pragma unroll
    for (int q = 0; q < 8; ++q) {
        float v[8];
#pragma unroll
        for (int c = 0; c < 8; ++c) {
            const float* p = s + (size_t)(q * 8 + c) * 4096;
            v[c] = w00 * p[i00] + w01 * p[i01] + w10 * p[i10] + w11 * p[i11];
        }
        uint4 u;
        u.x = pack2(v[0], v[1]); u.y = pack2(v[2], v[3]);
        u.z = pack2(v[4], v[5]); u.w = pack2(v[6], v[7]);
        *reinterpret_cast<uint4*>(d + q * 8) = u;
    }
}

// ---------------- implicit-GEMM conv via MFMA -------------------------------
// in : NHWC bf16, padded 130x130 when NS==9, raw 128x128 when NS==1
// wgt: bf16 [Mpad][NS*CIN] (shift-major k)
// out: NHWC bf16 (optionally padded) and/or NCHW fp32
// block = 256 thr = 4 waves; wave computes M=64 x N=32; block = one image row
template<int CIN, int NS, bool ACT, bool NHWC_OUT, bool OUT_PAD, bool NCHW_OUT>
__global__ __launch_bounds__(256) void conv_mfma(
    const u16* __restrict__ in, const u16* __restrict__ wgt,
    const float* __restrict__ bias,
    u16* __restrict__ outN, int c0, int Ctot,
    float* __restrict__ outC, int Cout) {
    constexpr int K = NS * CIN;
    constexpr bool INPAD = (NS == 9);
    constexpr int IW = INPAD ? 130 : 128;
    constexpr int IPIX = INPAD ? 16900 : 16384;
    const int lane = threadIdx.x & 63;
    const int wv = threadIdx.x >> 6;
    const int y = blockIdx.x & 127;
    const int b = blockIdx.x >> 7;
    const int mblk = blockIdx.y << 6;
    const int n0 = lane & 15;
    const int kq = lane >> 4;
    const int xbase = wv * 32;

    const u16* inB = in + (size_t)b * IPIX * CIN;
    const u16* wbase = wgt + (size_t)(mblk + n0) * K + kq * 8;

    f32x4 acc[4][2] = {};

#pragma unroll
    for (int s = 0; s < NS; ++s) {
        const int dy = s / 3 - 1, dx = s - (s / 3) * 3 - 1;
        const int yy = INPAD ? (y + 1 + dy) : y;
        const int xx0 = (INPAD ? (1 + dx) : 0) + xbase + n0;
        const u16* prow = inB + ((size_t)yy * IW + xx0) * CIN + kq * 8;
#pragma unroll
        for (int c = 0; c < CIN / 32; ++c) {
            const int k = s * CIN + c * 32;
            bf16x8 a0 = ld8(wbase + 0 * 16 * K + k);
            bf16x8 a1 = ld8(wbase + 1 * 16 * K + k);
            bf16x8 a2 = ld8(wbase + 2 * 16 * K + k);
            bf16x8 a3 = ld8(wbase + 3 * 16 * K + k);
            bf16x8 b0 = ld8(prow + c * 32);
            bf16x8 b1 = ld8(prow + 16 * CIN + c * 32);
            acc[0][0] = __builtin_amdgcn_mfma_f32_16x16x32_bf16(a0, b0, acc[0][0], 0, 0, 0);
            acc[0][1] = __builtin_amdgcn_mfma_f32_16x16x32_bf16(a0, b1, acc[0][1], 0, 0, 0);
            acc[1][0] = __builtin_amdgcn_mfma_f32_16x16x32_bf16(a1, b0, acc[1][0], 0, 0, 0);
            acc[1][1] = __builtin_amdgcn_mfma_f32_16x16x32_bf16(a1, b1, acc[1][1], 0, 0, 0);
            acc[2][0] = __builtin_amdgcn_mfma_f32_16x16x32_bf16(a2, b0, acc[2][0], 0, 0, 0);
            acc[2][1] = __builtin_amdgcn_mfma_f32_16x16x32_bf16(a2, b1, acc[2][1], 0, 0, 0);
            acc[3][0] = __builtin_amdgcn_mfma_f32_16x16x32_bf16(a3, b0, acc[3][0], 0, 0, 0);
            acc[3][1] = __builtin_amdgcn_mfma_f32_16x16x32_bf16(a3, b1, acc[3][1], 0, 0, 0);
        }
    }

    // epilogue: C/D layout col = lane&15, row = (lane>>4)*4 + j
#pragma unroll
    for (int mt = 0; mt < 4; ++mt) {
        const int mbase = mblk + mt * 16 + kq * 4;
        float bs0 = 0.f, bs1 = 0.f, bs2 = 0.f, bs3 = 0.f;
        if (mbase < Cout) {
            bs0 = bias[mbase]; bs1 = bias[mbase + 1];
            bs2 = bias[mbase + 2]; bs3 = bias[mbase + 3];
        }
#pragma unroll
        for (int nt = 0; nt < 2; ++nt) {
            const int xx = xbase + nt * 16 + n0;
            float v0 = acc[mt][nt][0] + bs0, v1 = acc[mt][nt][1] + bs1;
            float v2 = acc[mt][nt][2] + bs2, v3 = acc[mt][nt][3] + bs3;
            if (ACT) {
                v0 = (v0 >= 0.f) ? v0 : 0.1f * v0;
                v1 = (v1 >= 0.f) ? v1 : 0.1f * v1;
                v2 = (v2 >= 0.f) ? v2 : 0.1f * v2;
                v3 = (v3 >= 0.f) ? v3 : 0.1f * v3;
            }
            if (NHWC_OUT && mbase < Cout) {
                size_t pix = OUT_PAD ? ((size_t)(y + 1) * 130 + xx + 1)
                                     : ((size_t)y * 128 + xx);
                size_t off = ((size_t)b * (OUT_PAD ? 16900 : 16384) + pix) * Ctot + c0 + mbase;
                uint2 u;
                u.x = pack2(v0, v1); u.y = pack2(v2, v3);
                *reinterpret_cast<uint2*>(outN + off) = u;
            }
            if (NCHW_OUT && mbase < Cout) {
                size_t o = ((size_t)(b * 64 + mbase)) * 16384 + (size_t)y * 128 + xx;
                outC[o] = v0; outC[o + 16384] = v1;
                outC[o + 2 * 16384] = v2; outC[o + 3 * 16384] = v3;
            }
        }
    }
}

// ---------------- DCNv2 sampling -> val NHWC bf16 (k' = g*72 + kk*8 + c) -----
__global__ __launch_bounds__(256) void dcn_sample(
    const u16* __restrict__ xn,   // NHWC128-pad, x at channels 0..63
    const u16* __restrict__ co,   // NHWC216 raw
    u16* __restrict__ val) {      // NHWC576 raw
    int p = blockIdx.x * 256 + threadIdx.x;
    int gk = blockIdx.y;                       // 0..71
    int b = blockIdx.z;
    int g = gk / 9, kk = gk - g * 9;
    int xp = p & 127, yp = p >> 7;
    const u16* cop = co + ((size_t)b * 16384 + p) * 216;
    float offy = bf2f(cop[gk]);
    float offx = bf2f(cop[72 + gk]);
    float mv = 1.0f / (1.0f + expf(-bf2f(cop[144 + gk])));
    int ky = kk / 3 - 1, kx = kk - (kk / 3) * 3 - 1;
    float py = offy + (float)ky + (float)yp;
    float px = offx + (float)kx + (float)xp;
    float y0f = floorf(py), x0f = floorf(px);
    float wy = py - y0f, wx = px - x0f;
    int y0 = (int)y0f, x0 = (int)x0f, y1 = y0 + 1, x1 = x0 + 1;
    float m00 = ((unsigned)y0 < 128u && (unsigned)x0 < 128u) ? 1.f : 0.f;
    float m01 = ((unsigned)y0 < 128u && (unsigned)x1 < 128u) ? 1.f : 0.f;
    float m10 = ((unsigned)y1 < 128u && (unsigned)x0 < 128u) ? 1.f : 0.f;
    float m11 = ((unsigned)y1 < 128u && (unsigned)x1 < 128u) ? 1.f : 0.f;
    float w00 = (1.f - wy) * (1.f - wx) * m00, w01 = (1.f - wy) * wx * m01;
    float w10 = wy * (1.f - wx) * m10, w11 = wy * wx * m11;
    int y0c = min(max(y0, 0), 127), y1c = min(max(y1, 0), 127);
    int x0c = min(max(x0, 0), 127), x1c = min(max(x1, 0), 127);
    const u16* xb = xn + (size_t)b * 16900 * 128 + g * 8;
    uint4 q00 = *reinterpret_cast<const uint4*>(xb + ((size_t)(y0c + 1) * 130 + x0c + 1) * 128);
    uint4 q01 = *reinterpret_cast<const uint4*>(xb + ((size_t)(y0c + 1) * 130 + x1c + 1) * 128);
    uint4 q10 = *reinterpret_cast<const uint4*>(xb + ((size_t)(y1c + 1) * 130 + x0c + 1) * 128);
    uint4 q11 = *reinterpret_cast<const uint4*>(xb + ((size_t)(y1c + 1) * 130 + x1c + 1) * 128);
    const unsigned int* a00 = &q00.x; const unsigned int* a01 = &q01.x;
    const unsigned int* a10 = &q10.x; const unsigned int* a11 = &q11.x;
    float r[8];
#pragma unroll
    for (int c = 0; c < 8; ++c) {
        unsigned int u00 = a00[c >> 1], u01 = a01[c >> 1], u10 = a10[c >> 1], u11 = a11[c >> 1];
        int sh = (c & 1) * 16;
        float f00 = bf2f((u16)(u00 >> sh)), f01 = bf2f((u16)(u01 >> sh));
        float f10 = bf2f((u16)(u10 >> sh)), f11 = bf2f((u16)(u11 >> sh));
        r[c] = (w00 * f00 + w01 * f01 + w10 * f10 + w11 * f11) * mv;
    }
    size_t o = ((size_t)b * 16384 + p) * 576 + g * 72 + kk * 8;
    uint4 u;
    u.x = pack2(r[0], r[1]); u.y = pack2(r[2], r[3]);
    u.z = pack2(r[4], r[5]); u.w = pack2(r[6], r[7]);
    *reinterpret_cast<uint4*>(val + o) = u;
}

// ---------------- workspace layout (bytes) ----------------------------------
#define T1_OFF 0u               /* NHWC128-pad concat(x,y); later fea||up   8,652,800 */
#define T3_OFF 8652800u         /* NHWC128-pad off1||upPrev                 8,652,800 */
#define T4_OFF 17305600u        /* NHWC64-pad off2                          4,326,400 */
#define T5_OFF 21632000u        /* NHWC64-pad off                           4,326,400 */
#define T7_OFF 8652800u         /* NHWC576 val (reuses T3..T5)             37,748,736 */
#define T6_OFF 46401536u        /* NHWC216 co                              14,155,776 */
#define W1_OFF 60557312u
#define W2_OFF 60704768u
#define W3_OFF 60852224u
#define WF_OFF 60925952u
#define WO_OFF 61073408u        /* padded to 256 rows: 294,912 B */
#define WD_OFF 61368320u

extern "C" void kernel_launch(void* const* d_in, const int* in_sizes, int n_in,
                              void* d_out, int out_size, void* d_ws, size_t ws_size,
                              hipStream_t stream) {
    const float* x        = (const float*)d_in[0];
    const float* y        = (const float*)d_in[1];
    const float* prev_off = (const float*)d_in[2];
    const float* prev_fea = (const float*)d_in[3];
    const float* w1 = (const float*)d_in[4];  const float* b1 = (const float*)d_in[5];
    const float* w2 = (const float*)d_in[6];  const float* b2 = (const float*)d_in[7];
    const float* w3 = (const float*)d_in[8];  const float* b3 = (const float*)d_in[9];
    const float* w_off = (const float*)d_in[10]; const float* b_off = (const float*)d_in[11];
    const float* w_dcn = (const float*)d_in[12]; const float* b_dcn = (const float*)d_in[13];
    const float* w_fea = (const float*)d_in[14]; const float* b_fea = (const float*)d_in[15];

    float* out_off = (float*)d_out;
    float* out_out = (float*)d_out + (size_t)2 * 64 * 16384;

    char* ws = (char*)d_ws;
    u16* T1 = (u16*)(ws + T1_OFF);
    u16* T3 = (u16*)(ws + T3_OFF);
    u16* T4 = (u16*)(ws + T4_OFF);
    u16* T5 = (u16*)(ws + T5_OFF);
    u16* T6 = (u16*)(ws + T6_OFF);
    u16* T7 = (u16*)(ws + T7_OFF);
    u16* T8 = T1;
    u16* wq1 = (u16*)(ws + W1_OFF);
    u16* wq2 = (u16*)(ws + W2_OFF);
    u16* wq3 = (u16*)(ws + W3_OFF);
    u16* wqf = (u16*)(ws + WF_OFF);
    u16* wqo = (u16*)(ws + WO_OFF);
    u16* wqd = (u16*)(ws + WD_OFF);

    // zero padded borders (and w_off padding rows); interiors are overwritten
    hipMemsetAsync(T1, 0, 8652800, stream);
    hipMemsetAsync(T3, 0, 8652800, stream);
    hipMemsetAsync(T4, 0, 4326400, stream);
    hipMemsetAsync(T5, 0, 4326400, stream);
    hipMemsetAsync(wqo, 0, 294912, stream);

    dim3 blk(256);
    // weight repacks
    repack_w<<<dim3((64 * 128 * 9 + 255) / 256), blk, 0, stream>>>(w1, wq1, 64, 128, 1152, 0);
    repack_w<<<dim3((64 * 128 * 9 + 255) / 256), blk, 0, stream>>>(w2, wq2, 64, 128, 1152, 0);
    repack_w<<<dim3((64 * 64 * 9 + 255) / 256), blk, 0, stream>>>(w3, wq3, 64, 64, 576, 0);
    repack_w<<<dim3((216 * 64 * 9 + 255) / 256), blk, 0, stream>>>(w_off, wqo, 216, 64, 576, 0);
    repack_w<<<dim3((64 * 64 * 9 + 255) / 256), blk, 0, stream>>>(w_dcn, wqd, 64, 64, 576, 1);
    repack_w<<<dim3((64 * 128 * 9 + 255) / 256), blk, 0, stream>>>(w_fea, wqf, 64, 128, 1152, 0);

    // inputs -> NHWC bf16
    to_nhwc<<<dim3(128), blk, 0, stream>>>(x, T1, 0, 128);
    to_nhwc<<<dim3(128), blk, 0, stream>>>(y, T1, 64, 128);
    up2_nhwc<<<dim3(128), blk, 0, stream>>>(prev_off, T3, 64, 128, 2.0f);

    // conv1: concat(x,y) -> off1 (into T3 ch0..63)
    conv_mfma<128, 9, true, true, true, false><<<dim3(256, 1), blk, 0, stream>>>(
        T1, wq1, b1, T3, 0, 128, nullptr, 64);
    // conv2: concat(off1, upPrev*2) -> off2 (T4)
    conv_mfma<128, 9, true, true, true, false><<<dim3(256, 1), blk, 0, stream>>>(
        T3, wq2, b2, T4, 0, 64, nullptr, 64);
    // conv3: off2 -> off (T5 + output0 NCHW)
    conv_mfma<64, 9, true, true, true, true><<<dim3(256, 1), blk, 0, stream>>>(
        T4, wq3, b3, T5, 0, 64, out_off, 64);
    // conv_off: off -> co (T6, 216ch, no act)
    conv_mfma<64, 9, false, true, false, false><<<dim3(256, 4), blk, 0, stream>>>(
        T5, wqo, b_off, T6, 0, 216, nullptr, 216);
    // DCN sampling -> val (T7)
    dcn_sample<<<dim3(64, 72, 2), blk, 0, stream>>>(T1, T6, T7);
    // DCN einsum (K=576 GEMM) -> fea (T8 ch0..63; T8 aliases T1, borders already 0)
    conv_mfma<576, 1, false, true, true, false><<<dim3(256, 1), blk, 0, stream>>>(
        T7, wqd, b_dcn, T8, 0, 128, nullptr, 64);
    // up(prev_stage_fea) -> T8 ch64..127
    up2_nhwc<<<dim3(128), blk, 0, stream>>>(prev_fea, T8, 64, 128, 1.0f);
    // final conv: concat(fea, upFea) -> output1 NCHW
    conv_mfma<128, 9, true, false, false, true><<<dim3(256, 1), blk, 0, stream>>>(
        T8, wqf, b_fea, nullptr, 0, 0, out_out, 64);
}

// Round 3
// 254.750 us; speedup vs baseline: 3.8585x; 1.1795x over previous
//
#include <hip/hip_runtime.h>
#include <math.h>

typedef __bf16 bf16x8 __attribute__((ext_vector_type(8)));
typedef float f32x4 __attribute__((ext_vector_type(4)));
typedef unsigned short u16;

// ---------------- helpers ----------------
__device__ __forceinline__ u16 f2bf(float f) {
    unsigned int u = __builtin_bit_cast(unsigned int, f);
    unsigned int r = (u + 0x7FFFu + ((u >> 16) & 1u)) >> 16;   // RNE
    return (u16)r;
}
__device__ __forceinline__ float bf2f(u16 u) {
    unsigned int v = ((unsigned int)u) << 16;
    return __builtin_bit_cast(float, v);
}
__device__ __forceinline__ unsigned int pack2(float a, float b) {
    return (unsigned int)f2bf(a) | ((unsigned int)f2bf(b) << 16);
}
__device__ __forceinline__ bf16x8 ld8(const u16* p) {
    uint4 u = *reinterpret_cast<const uint4*>(p);
    return __builtin_bit_cast(bf16x8, u);
}

// ---------------- weight repack: [Co][Ci][3][3] f32 -> bf16 GEMM-A layout ----
// mode 0: dst[o*K + kk*Cin + ci]          (K = 9*Cin, shift-major)
// mode 1: dst[o*576 + (ci>>3)*72 + kk*8 + (ci&7)]   (dcn sample order)
__global__ __launch_bounds__(256) void repack_w(const float* __restrict__ w,
                                                u16* __restrict__ dst,
                                                int Cout, int Cin, int K, int mode) {
    int idx = blockIdx.x * 256 + threadIdx.x;
    int total = Cout * Cin * 9;
    if (idx >= total) return;
    int kk = idx % 9;
    int t = idx / 9;
    int ci = t % Cin;
    int o = t / Cin;
    u16 v = f2bf(w[idx]);
    size_t d;
    if (mode == 0) d = (size_t)o * K + kk * Cin + ci;
    else           d = (size_t)o * 576 + (ci >> 3) * 72 + kk * 8 + (ci & 7);
    dst[d] = v;
}

// ---------------- NCHW f32 [B][64][128][128] -> NHWC-pad bf16 at channel c0 --
__global__ __launch_bounds__(256) void to_nhwc(const float* __restrict__ src,
                                               u16* __restrict__ dst,
                                               int c0, int Ctot) {
    int idx = blockIdx.x * 256 + threadIdx.x;   // b*16384 + pix
    int pix = idx & 16383, b = idx >> 14;
    int y = pix >> 7, x = pix & 127;
    const float* s = src + (size_t)b * 64 * 16384 + pix;
    u16* d = dst + (((size_t)b * 16900) + (size_t)(y + 1) * 130 + (x + 1)) * Ctot + c0;
#pragma unroll
    for (int q = 0; q < 8; ++q) {
        float v0 = s[(size_t)(q * 8 + 0) * 16384], v1 = s[(size_t)(q * 8 + 1) * 16384];
        float v2 = s[(size_t)(q * 8 + 2) * 16384], v3 = s[(size_t)(q * 8 + 3) * 16384];
        float v4 = s[(size_t)(q * 8 + 4) * 16384], v5 = s[(size_t)(q * 8 + 5) * 16384];
        float v6 = s[(size_t)(q * 8 + 6) * 16384], v7 = s[(size_t)(q * 8 + 7) * 16384];
        uint4 u;
        u.x = pack2(v0, v1); u.y = pack2(v2, v3); u.z = pack2(v4, v5); u.w = pack2(v6, v7);
        *reinterpret_cast<uint4*>(d + q * 8) = u;
    }
}

// ---------------- bilinear up2 (align_corners) + scale -> NHWC-pad bf16 ------
__global__ __launch_bounds__(256) void up2_nhwc(const float* __restrict__ src, // [B][64][64][64]
                                                u16* __restrict__ dst,
                                                int c0, int Ctot, float scale) {
    int idx = blockIdx.x * 256 + threadIdx.x;
    int pix = idx & 16383, b = idx >> 14;
    int y = pix >> 7, x = pix & 127;
    const float f = 63.0f / 127.0f;
    float cy = y * f, cx = x * f;
    float y0f = floorf(cy), x0f = floorf(cx);
    int y0 = (int)y0f, x0 = (int)x0f;
    int y1 = min(y0 + 1, 63), x1 = min(x0 + 1, 63);
    float fy = cy - y0f, fx = cx - x0f;
    float w00 = (1.f - fy) * (1.f - fx) * scale, w01 = (1.f - fy) * fx * scale;
    float w10 = fy * (1.f - fx) * scale, w11 = fy * fx * scale;
    int i00 = y0 * 64 + x0, i01 = y0 * 64 + x1, i10 = y1 * 64 + x0, i11 = y1 * 64 + x1;
    const float* s = src + (size_t)b * 64 * 4096;
    u16* d = dst + (((size_t)b * 16900) + (size_t)(y + 1) * 130 + (x + 1)) * Ctot + c0;
#pragma unroll
    for (int q = 0; q < 8; ++q) {
        float v[8];
#pragma unroll
        for (int c = 0; c < 8; ++c) {
            const float* p = s + (size_t)(q * 8 + c) * 4096;
            v[c] = w00 * p[i00] + w01 * p[i01] + w10 * p[i10] + w11 * p[i11];
        }
        uint4 u;
        u.x = pack2(v[0], v[1]); u.y = pack2(v[2], v[3]);
        u.z = pack2(v[4], v[5]); u.w = pack2(v[6], v[7]);
        *reinterpret_cast<uint4*>(d + q * 8) = u;
    }
}

// ---------------- implicit-GEMM conv via MFMA -------------------------------
// in : NHWC bf16, padded 130x130; wgt: bf16 [Mpad][9*CIN] (shift-major k)
// ACTM: 0 none, 1 lrelu, 2 sigmoid-on-channels>=144
// block = 256 thr = 4 waves; wave computes M=64 x N=32; block = one image row
template<int CIN, int ACTM, bool NHWC_OUT, bool OUT_PAD, bool NCHW_OUT>
__global__ __launch_bounds__(256) void conv_mfma(
    const u16* __restrict__ in, const u16* __restrict__ wgt,
    const float* __restrict__ bias,
    u16* __restrict__ outN, int c0, int Ctot,
    float* __restrict__ outC, int Cout) {
    constexpr int K = 9 * CIN;
    const int lane = threadIdx.x & 63;
    const int wv = threadIdx.x >> 6;
    const int y = blockIdx.x & 127;
    const int b = blockIdx.x >> 7;
    const int mblk = blockIdx.y << 6;
    const int n0 = lane & 15;
    const int kq = lane >> 4;
    const int xbase = wv * 32;

    const u16* inB = in + (size_t)b * 16900 * CIN;
    const u16* wbase = wgt + (size_t)(mblk + n0) * K + kq * 8;

    f32x4 acc[4][2] = {};

#pragma unroll
    for (int s = 0; s < 9; ++s) {
        const int dy = s / 3 - 1, dx = s - (s / 3) * 3 - 1;
        const int yy = y + 1 + dy;
        const int xx0 = 1 + dx + xbase + n0;
        const u16* prow = inB + ((size_t)yy * 130 + xx0) * CIN + kq * 8;
#pragma unroll
        for (int c = 0; c < CIN / 32; ++c) {
            const int k = s * CIN + c * 32;
            bf16x8 a0 = ld8(wbase + 0 * 16 * K + k);
            bf16x8 a1 = ld8(wbase + 1 * 16 * K + k);
            bf16x8 a2 = ld8(wbase + 2 * 16 * K + k);
            bf16x8 a3 = ld8(wbase + 3 * 16 * K + k);
            bf16x8 b0 = ld8(prow + c * 32);
            bf16x8 b1 = ld8(prow + 16 * CIN + c * 32);
            acc[0][0] = __builtin_amdgcn_mfma_f32_16x16x32_bf16(a0, b0, acc[0][0], 0, 0, 0);
            acc[0][1] = __builtin_amdgcn_mfma_f32_16x16x32_bf16(a0, b1, acc[0][1], 0, 0, 0);
            acc[1][0] = __builtin_amdgcn_mfma_f32_16x16x32_bf16(a1, b0, acc[1][0], 0, 0, 0);
            acc[1][1] = __builtin_amdgcn_mfma_f32_16x16x32_bf16(a1, b1, acc[1][1], 0, 0, 0);
            acc[2][0] = __builtin_amdgcn_mfma_f32_16x16x32_bf16(a2, b0, acc[2][0], 0, 0, 0);
            acc[2][1] = __builtin_amdgcn_mfma_f32_16x16x32_bf16(a2, b1, acc[2][1], 0, 0, 0);
            acc[3][0] = __builtin_amdgcn_mfma_f32_16x16x32_bf16(a3, b0, acc[3][0], 0, 0, 0);
            acc[3][1] = __builtin_amdgcn_mfma_f32_16x16x32_bf16(a3, b1, acc[3][1], 0, 0, 0);
        }
    }

    // epilogue: C/D layout col = lane&15, row = (lane>>4)*4 + j
#pragma unroll
    for (int mt = 0; mt < 4; ++mt) {
        const int mbase = mblk + mt * 16 + kq * 4;
        float bs0 = 0.f, bs1 = 0.f, bs2 = 0.f, bs3 = 0.f;
        if (mbase < Cout) {
            bs0 = bias[mbase]; bs1 = bias[mbase + 1];
            bs2 = bias[mbase + 2]; bs3 = bias[mbase + 3];
        }
#pragma unroll
        for (int nt = 0; nt < 2; ++nt) {
            const int xx = xbase + nt * 16 + n0;
            float v0 = acc[mt][nt][0] + bs0, v1 = acc[mt][nt][1] + bs1;
            float v2 = acc[mt][nt][2] + bs2, v3 = acc[mt][nt][3] + bs3;
            if (ACTM == 1) {
                v0 = (v0 >= 0.f) ? v0 : 0.1f * v0;
                v1 = (v1 >= 0.f) ? v1 : 0.1f * v1;
                v2 = (v2 >= 0.f) ? v2 : 0.1f * v2;
                v3 = (v3 >= 0.f) ? v3 : 0.1f * v3;
            } else if (ACTM == 2) {
                if (mbase >= 144) {
                    v0 = 1.f / (1.f + expf(-v0));
                    v1 = 1.f / (1.f + expf(-v1));
                    v2 = 1.f / (1.f + expf(-v2));
                    v3 = 1.f / (1.f + expf(-v3));
                }
            }
            if (NHWC_OUT && mbase < Cout) {
                size_t pix = OUT_PAD ? ((size_t)(y + 1) * 130 + xx + 1)
                                     : ((size_t)y * 128 + xx);
                size_t off = ((size_t)b * (OUT_PAD ? 16900 : 16384) + pix) * Ctot + c0 + mbase;
                uint2 u;
                u.x = pack2(v0, v1); u.y = pack2(v2, v3);
                *reinterpret_cast<uint2*>(outN + off) = u;
            }
            if (NCHW_OUT && mbase < Cout) {
                size_t o = ((size_t)(b * Cout + mbase)) * 16384 + (size_t)y * 128 + xx;
                outC[o] = v0; outC[o + 16384] = v1;
                outC[o + 2 * 16384] = v2; outC[o + 3 * 16384] = v3;
            }
        }
    }
}

// ---------------- fused DCNv2: sample in-register + K=576 MFMA GEMM ---------
// xn : NHWC128-pad bf16 (x at ch 0..63)
// co : NCHW fp32 [b][216][16384]; ch>=144 already sigmoided
// wgt: bf16 [64][576] in sample order (g*72 + kk*8 + c)
// out: fea -> NHWC128-pad ch 0..63
// block = 256 thr = 4 waves; wave computes M=64(outch) x N=16(pixels)
__global__ __launch_bounds__(256) void dcn_fused(
    const u16* __restrict__ xn, const float* __restrict__ co,
    const u16* __restrict__ wgt, const float* __restrict__ bias,
    u16* __restrict__ outN) {
    __shared__ u16 lw[64 * 584];      // padded stride 584 (bank-spread)
    {
        int t = threadIdx.x;
        int o = t >> 2, chunk = t & 3;
        const u16* src = wgt + o * 576 + chunk * 144;
        u16* dst = lw + o * 584 + chunk * 144;
#pragma unroll
        for (int i = 0; i < 18; ++i)
            *reinterpret_cast<uint4*>(dst + i * 8) =
                *reinterpret_cast<const uint4*>(src + i * 8);
    }
    __syncthreads();

    const int lane = threadIdx.x & 63;
    const int wv = threadIdx.x >> 6;
    const int half = blockIdx.x & 1;
    const int y = (blockIdx.x >> 1) & 127;
    const int b = blockIdx.x >> 8;
    const int n0 = lane & 15;
    const int kq = lane >> 4;
    const int xx = half * 64 + wv * 16 + n0;
    const int p = y * 128 + xx;

    const float* cob = co + (size_t)b * 216 * 16384 + p;
    const u16* xb = xn + (size_t)b * 16900 * 128;

    f32x4 acc[4] = {};

#pragma unroll 3
    for (int cs = 0; cs < 18; ++cs) {
        int gk8 = cs * 4 + kq;                 // 0..71  (= g*9+kk)
        int g = (gk8 * 57) >> 9;               // /9
        int kk = gk8 - 9 * g;
        int ky = (kk * 11) >> 5;               // /3
        int kx = kk - 3 * ky;
        float offy = cob[(size_t)gk8 * 16384];
        float offx = cob[(size_t)(72 + gk8) * 16384];
        float mv   = cob[(size_t)(144 + gk8) * 16384];   // pre-sigmoided
        float py = offy + (float)(ky - 1) + (float)y;
        float px = offx + (float)(kx - 1) + (float)xx;
        float y0f = floorf(py), x0f = floorf(px);
        float wy = py - y0f, wx = px - x0f;
        int y0 = (int)y0f, x0 = (int)x0f, y1 = y0 + 1, x1 = x0 + 1;
        float m00 = ((unsigned)y0 < 128u && (unsigned)x0 < 128u) ? 1.f : 0.f;
        float m01 = ((unsigned)y0 < 128u && (unsigned)x1 < 128u) ? 1.f : 0.f;
        float m10 = ((unsigned)y1 < 128u && (unsigned)x0 < 128u) ? 1.f : 0.f;
        float m11 = ((unsigned)y1 < 128u && (unsigned)x1 < 128u) ? 1.f : 0.f;
        float w00 = (1.f - wy) * (1.f - wx) * m00 * mv;
        float w01 = (1.f - wy) * wx * m01 * mv;
        float w10 = wy * (1.f - wx) * m10 * mv;
        float w11 = wy * wx * m11 * mv;
        int y0c = min(max(y0, 0), 127), y1c = min(max(y1, 0), 127);
        int x0c = min(max(x0, 0), 127), x1c = min(max(x1, 0), 127);
        const u16* xg = xb + g * 8;
        uint4 q00 = *reinterpret_cast<const uint4*>(xg + ((size_t)(y0c + 1) * 130 + x0c + 1) * 128);
        uint4 q01 = *reinterpret_cast<const uint4*>(xg + ((size_t)(y0c + 1) * 130 + x1c + 1) * 128);
        uint4 q10 = *reinterpret_cast<const uint4*>(xg + ((size_t)(y1c + 1) * 130 + x0c + 1) * 128);
        uint4 q11 = *reinterpret_cast<const uint4*>(xg + ((size_t)(y1c + 1) * 130 + x1c + 1) * 128);
        const unsigned int* a00 = &q00.x; const unsigned int* a01 = &q01.x;
        const unsigned int* a10 = &q10.x; const unsigned int* a11 = &q11.x;
        float r[8];
#pragma unroll
        for (int c = 0; c < 8; ++c) {
            unsigned int u00 = a00[c >> 1], u01 = a01[c >> 1];
            unsigned int u10 = a10[c >> 1], u11 = a11[c >> 1];
            int sh = (c & 1) * 16;
            float f00 = bf2f((u16)(u00 >> sh)), f01 = bf2f((u16)(u01 >> sh));
            float f10 = bf2f((u16)(u10 >> sh)), f11 = bf2f((u16)(u11 >> sh));
            r[c] = w00 * f00 + w01 * f01 + w10 * f10 + w11 * f11;
        }
        uint4 bu;
        bu.x = pack2(r[0], r[1]); bu.y = pack2(r[2], r[3]);
        bu.z = pack2(r[4], r[5]); bu.w = pack2(r[6], r[7]);
        bf16x8 bfrag = __builtin_bit_cast(bf16x8, bu);

        const int kcol = cs * 32 + kq * 8;
        bf16x8 a0 = ld8(lw + (size_t)(0 * 16 + n0) * 584 + kcol);
        bf16x8 a1 = ld8(lw + (size_t)(1 * 16 + n0) * 584 + kcol);
        bf16x8 a2 = ld8(lw + (size_t)(2 * 16 + n0) * 584 + kcol);
        bf16x8 a3 = ld8(lw + (size_t)(3 * 16 + n0) * 584 + kcol);
        acc[0] = __builtin_amdgcn_mfma_f32_16x16x32_bf16(a0, bfrag, acc[0], 0, 0, 0);
        acc[1] = __builtin_amdgcn_mfma_f32_16x16x32_bf16(a1, bfrag, acc[1], 0, 0, 0);
        acc[2] = __builtin_amdgcn_mfma_f32_16x16x32_bf16(a2, bfrag, acc[2], 0, 0, 0);
        acc[3] = __builtin_amdgcn_mfma_f32_16x16x32_bf16(a3, bfrag, acc[3], 0, 0, 0);
    }

    // epilogue: fea -> NHWC128-pad ch0..63
#pragma unroll
    for (int mt = 0; mt < 4; ++mt) {
        const int mbase = mt * 16 + kq * 4;
        float v0 = acc[mt][0] + bias[mbase];
        float v1 = acc[mt][1] + bias[mbase + 1];
        float v2 = acc[mt][2] + bias[mbase + 2];
        float v3 = acc[mt][3] + bias[mbase + 3];
        size_t off = ((size_t)b * 16900 + (size_t)(y + 1) * 130 + (xx + 1)) * 128 + mbase;
        uint2 u;
        u.x = pack2(v0, v1); u.y = pack2(v2, v3);
        *reinterpret_cast<uint2*>(outN + off) = u;
    }
}

// ---------------- workspace layout (bytes) ----------------------------------
#define T1_OFF 0u            /* NHWC128-pad x||y                 8,652,800 */
#define T3_OFF 8652800u      /* NHWC128-pad off1||upPrev; later fea||upFea */
#define T4_OFF 17305600u     /* NHWC64-pad off2                  4,326,400 */
#define T5_OFF 21632000u     /* NHWC64-pad off                   4,326,400 */
#define T6_OFF 25958400u     /* co fp32 NCHW [2][216][16384]    28,311,552 */
#define W1_OFF 54269952u
#define W2_OFF 54417408u
#define W3_OFF 54564864u
#define WF_OFF 54638592u
#define WO_OFF 54786048u     /* padded to 256 rows: 294,912 B */
#define WD_OFF 55080960u

extern "C" void kernel_launch(void* const* d_in, const int* in_sizes, int n_in,
                              void* d_out, int out_size, void* d_ws, size_t ws_size,
                              hipStream_t stream) {
    const float* x        = (const float*)d_in[0];
    const float* y        = (const float*)d_in[1];
    const float* prev_off = (const float*)d_in[2];
    const float* prev_fea = (const float*)d_in[3];
    const float* w1 = (const float*)d_in[4];  const float* b1 = (const float*)d_in[5];
    const float* w2 = (const float*)d_in[6];  const float* b2 = (const float*)d_in[7];
    const float* w3 = (const float*)d_in[8];  const float* b3 = (const float*)d_in[9];
    const float* w_off = (const float*)d_in[10]; const float* b_off = (const float*)d_in[11];
    const float* w_dcn = (const float*)d_in[12]; const float* b_dcn = (const float*)d_in[13];
    const float* w_fea = (const float*)d_in[14]; const float* b_fea = (const float*)d_in[15];

    float* out_off = (float*)d_out;
    float* out_out = (float*)d_out + (size_t)2 * 64 * 16384;

    char* ws = (char*)d_ws;
    u16* T1 = (u16*)(ws + T1_OFF);
    u16* T3 = (u16*)(ws + T3_OFF);
    u16* T4 = (u16*)(ws + T4_OFF);
    u16* T5 = (u16*)(ws + T5_OFF);
    float* T6 = (float*)(ws + T6_OFF);
    u16* T8 = T3;
    u16* wq1 = (u16*)(ws + W1_OFF);
    u16* wq2 = (u16*)(ws + W2_OFF);
    u16* wq3 = (u16*)(ws + W3_OFF);
    u16* wqf = (u16*)(ws + WF_OFF);
    u16* wqo = (u16*)(ws + WO_OFF);
    u16* wqd = (u16*)(ws + WD_OFF);

    // zero padded borders; interiors are overwritten
    hipMemsetAsync(T1, 0, 8652800, stream);
    hipMemsetAsync(T3, 0, 8652800, stream);
    hipMemsetAsync(T4, 0, 4326400, stream);
    hipMemsetAsync(T5, 0, 4326400, stream);
    hipMemsetAsync(wqo, 0, 294912, stream);

    dim3 blk(256);
    // weight repacks
    repack_w<<<dim3((64 * 128 * 9 + 255) / 256), blk, 0, stream>>>(w1, wq1, 64, 128, 1152, 0);
    repack_w<<<dim3((64 * 128 * 9 + 255) / 256), blk, 0, stream>>>(w2, wq2, 64, 128, 1152, 0);
    repack_w<<<dim3((64 * 64 * 9 + 255) / 256), blk, 0, stream>>>(w3, wq3, 64, 64, 576, 0);
    repack_w<<<dim3((216 * 64 * 9 + 255) / 256), blk, 0, stream>>>(w_off, wqo, 216, 64, 576, 0);
    repack_w<<<dim3((64 * 64 * 9 + 255) / 256), blk, 0, stream>>>(w_dcn, wqd, 64, 64, 576, 1);
    repack_w<<<dim3((64 * 128 * 9 + 255) / 256), blk, 0, stream>>>(w_fea, wqf, 64, 128, 1152, 0);

    // inputs -> NHWC bf16
    to_nhwc<<<dim3(128), blk, 0, stream>>>(x, T1, 0, 128);
    to_nhwc<<<dim3(128), blk, 0, stream>>>(y, T1, 64, 128);
    up2_nhwc<<<dim3(128), blk, 0, stream>>>(prev_off, T3, 64, 128, 2.0f);

    // conv1: concat(x,y) -> off1 (into T3 ch0..63)
    conv_mfma<128, 1, true, true, false><<<dim3(256, 1), blk, 0, stream>>>(
        T1, wq1, b1, T3, 0, 128, nullptr, 64);
    // conv2: concat(off1, upPrev*2) -> off2 (T4)
    conv_mfma<128, 1, true, true, false><<<dim3(256, 1), blk, 0, stream>>>(
        T3, wq2, b2, T4, 0, 64, nullptr, 64);
    // up(prev_stage_fea) -> T8 ch64..127  (T3 dead after conv2)
    up2_nhwc<<<dim3(128), blk, 0, stream>>>(prev_fea, T8, 64, 128, 1.0f);
    // conv3: off2 -> off (T5 + output0 NCHW)
    conv_mfma<64, 1, true, true, true><<<dim3(256, 1), blk, 0, stream>>>(
        T4, wq3, b3, T5, 0, 64, out_off, 64);
    // conv_off: off -> co NCHW fp32, sigmoid on ch>=144
    conv_mfma<64, 2, false, false, true><<<dim3(256, 4), blk, 0, stream>>>(
        T5, wqo, b_off, nullptr, 0, 0, T6, 216);
    // fused DCN: sample + K=576 GEMM -> fea (T8 ch0..63)
    dcn_fused<<<dim3(512), blk, 0, stream>>>(T1, T6, wqd, b_dcn, T8);
    // final conv: concat(fea, upFea) -> output1 NCHW
    conv_mfma<128, 1, false, false, true><<<dim3(256, 1), blk, 0, stream>>>(
        T8, wqf, b_fea, nullptr, 0, 0, out_out, 64);
}